// Round 11
// baseline (66.305 us; speedup 1.0000x reference)
//
#include <hip/hip_runtime.h>

// Policy MLP via split-precision bf16 MFMA (round 11: 16-col waves, 8/SIMD).
// B=131072, D=32, L=40 hidden + final 32->1.
//
// Round-11 change vs round 10: occupancy x2 + per-wave serial chain halved.
//  * Each wave handles ONE 16x16 output tile (16 batch cols): 2 accumulators,
//    6 MFMAs/layer, half the conversion VALU of the 32-col version.
//  * 8192 waves total; 512-thread blocks, __launch_bounds__(512,8):
//    4 blocks/CU -> 32 waves/CU = 8 waves/SIMD (was 4). Rationale: r3-r10 all
//    show VALUBusy+MfmaUtil ~ 85-97% (pipes serializing); more waves let one
//    wave's split phase overlap another's MFMA phase.
//  * No LDS staging (bought only 8% in r10; L1 absorbs the shared weight
//    reads, and LDS would cap blocks/CU at 1).
//
// Math structure per layer (unchanged): 3-term split-precision
//   acc = Whi*xhi (C = fp32 bias) ; += Wlo*xhi ; += Whi*xlo
// k-permutation pi(g,j) = 4g+j (j<4) | 16+4g+(j-4), g=lane>>4, applied to
// both A-tables and B-activations so D's natural layout (col=lane&15,
// row=4g+reg) feeds the next layer's B slots in-lane; truncation split via
// v_perm_b32 (hi's rounding error is carried exactly by lo).

#define NB 131072
#define DD 32
#define NL 40
#define BIAS_BYTES ((NL + 1) * 32 * 4)       // 5248, compact fp32 bias
#define WTAB_OFF   BIAS_BYTES
#define WTAB_BYTES ((NL + 1) * 4 * 64 * 16)  // 167936

typedef short bf16x8 __attribute__((ext_vector_type(8)));
typedef float f32x4 __attribute__((ext_vector_type(4)));

union Frag { int4 q; int i[4]; bf16x8 v; };
union BFrag { float4 q; f32x4 v; };

__device__ inline unsigned f2bf(float f) {  // fp32 -> bf16 bits, RNE
  unsigned u = __float_as_uint(f);
  return (u + 0x7fffu + ((u >> 16) & 1u)) >> 16;
}
__device__ inline float bf2f(unsigned s) { return __int_as_float((int)(s << 16)); }

// ---- table build ----------------------------------------------------------
// d_ws layout: [bias compact 5248 B][wtab 41 layers x 4096 B].
// wtab[l][p][lane]: p=0: W[m][pi] hi, p=1: W[16+m][pi] hi, p=2/3: lo parts.
__global__ __launch_bounds__(64) void build_tables(
    const float* __restrict__ Wh, const float* __restrict__ bh,
    const float* __restrict__ Wout, const float* __restrict__ bout,
    char* __restrict__ ws) {
  const int l = blockIdx.x;      // 0..40 (40 == output layer)
  const int lane = threadIdx.x;  // 0..63
  const int m = lane & 15, g = lane >> 4;
  int4* wtab = (int4*)(ws + WTAB_OFF);
  float* bc = (float*)ws;
  for (int p = 0; p < 4; ++p) {
    const int row = (p & 1) ? (16 + m) : m;
    const bool lopart = (p >= 2);
    int wds[4];
    for (int w = 0; w < 4; ++w) {
      unsigned wd = 0;
      for (int e = 0; e < 2; ++e) {
        const int j = 2 * w + e;
        const int k = (j < 4) ? (4 * g + j) : (16 + 4 * g + (j - 4));  // pi
        float v;
        if (l < NL) v = Wh[(l * 32 + row) * 32 + k];
        else        v = (row == 0) ? Wout[k] : 0.f;  // final: row0 = W_out
        unsigned hi = f2bf(v);
        unsigned val = lopart ? f2bf(v - bf2f(hi)) : hi;
        wd |= val << (16 * e);
      }
      wds[w] = (int)wd;
    }
    wtab[(l * 4 + p) * 64 + lane] = make_int4(wds[0], wds[1], wds[2], wds[3]);
  }
  if (lane < 32) {  // compact bias, one float per output row
    float bv = (l < NL) ? bh[l * 32 + lane] : ((lane == 0) ? bout[0] : 0.f);
    bc[l * 32 + lane] = bv;
  }
}

// ---- main kernel ----------------------------------------------------------
// Truncation split: hi = packed high-halves of (a,b) via one v_perm_b32;
// lo = packed high-halves of the exact residuals.
__device__ inline void split2(float a, float b, int& hi, int& lo) {
  const unsigned ia = __float_as_uint(a), ib = __float_as_uint(b);
  hi = (int)__builtin_amdgcn_perm(ia, ib, 0x03020706u);
  const float ha = __int_as_float((int)(ia & 0xffff0000u));
  const float hb = __int_as_float((int)(ib & 0xffff0000u));
  const float la = a - ha, lb = b - hb;  // exact
  lo = (int)__builtin_amdgcn_perm(__float_as_uint(la), __float_as_uint(lb),
                                  0x03020706u);
}

#define MFMA16(A, B, C) __builtin_amdgcn_mfma_f32_16x16x32_bf16((A), (B), (C), 0, 0, 0)

__global__ __launch_bounds__(512, 8) void policy_mfma(
    const float* __restrict__ state, const char* __restrict__ tab,
    float* __restrict__ out) {
  const int tid = threadIdx.x;
  const int lane = tid & 63;
  const int n = lane & 15, g = lane >> 4;
  const int wid = blockIdx.x * 8 + (tid >> 6);
  const int bbase = wid * 16;  // 16 batch cols per wave

  const int4* wp = (const int4*)(tab + WTAB_OFF) + lane;
  const float* bc = (const float*)tab;

  // Layer-0 B frag: slots j<4 <- x[4g+j], j>=4 <- x[16+4g+(j-4)]
  Frag bhi, blo;
  {
    const float* xr = state + (size_t)(bbase + n) * DD;
    float4 xa = *(const float4*)(xr + 4 * g);
    float4 xc = *(const float4*)(xr + 16 + 4 * g);
    split2(xa.x, xa.y, bhi.i[0], blo.i[0]);
    split2(xa.z, xa.w, bhi.i[1], blo.i[1]);
    split2(xc.x, xc.y, bhi.i[2], blo.i[2]);
    split2(xc.z, xc.w, bhi.i[3], blo.i[3]);
  }

  // ---- 40 hidden layers, fully unrolled ----
#pragma unroll
  for (int l = 0; l < NL; ++l) {
    Frag w0h, w1h, w0l, w1l;
    w0h.q = wp[l * 256 + 0];
    w1h.q = wp[l * 256 + 64];
    w0l.q = wp[l * 256 + 128];
    w1l.q = wp[l * 256 + 192];
    BFrag c0, c1;
    c0.q = *(const float4*)(bc + l * 32 + 4 * g);       // rows 4g..4g+3
    c1.q = *(const float4*)(bc + l * 32 + 16 + 4 * g);  // rows 16+4g..

    // two independent 3-deep chains
    f32x4 a0 = MFMA16(w0h.v, bhi.v, c0.v);
    f32x4 a1 = MFMA16(w1h.v, bhi.v, c1.v);
    a0 = MFMA16(w0l.v, bhi.v, a0);
    a1 = MFMA16(w1l.v, bhi.v, a1);
    a0 = MFMA16(w0h.v, blo.v, a0);
    a1 = MFMA16(w1h.v, blo.v, a1);

    // relu + trunc-split; a0 reg r -> slot r (rows 4g+r), a1 -> slot 4+r
    split2(fmaxf(a0[0], 0.f), fmaxf(a0[1], 0.f), bhi.i[0], blo.i[0]);
    split2(fmaxf(a0[2], 0.f), fmaxf(a0[3], 0.f), bhi.i[1], blo.i[1]);
    split2(fmaxf(a1[0], 0.f), fmaxf(a1[1], 0.f), bhi.i[2], blo.i[2]);
    split2(fmaxf(a1[2], 0.f), fmaxf(a1[3], 0.f), bhi.i[3], blo.i[3]);
  }

  // ---- final layer (W rows 16-31 zero: only w0h/w0l; row 0 = W_out) ----
  float res;
  {
    Frag w0h, w0l;
    w0h.q = wp[NL * 256 + 0];
    w0l.q = wp[NL * 256 + 128];
    BFrag c0;
    c0.q = *(const float4*)(bc + NL * 32 + 4 * g);
    f32x4 a0 = MFMA16(w0h.v, bhi.v, c0.v);
    a0 = MFMA16(w0l.v, bhi.v, a0);
    a0 = MFMA16(w0h.v, blo.v, a0);
    res = a0[0];  // row 0 lives in reg 0 of lanes g==0 (lane<16)
  }

  if (lane < 16) out[bbase + n] = res;
}

extern "C" void kernel_launch(void* const* d_in, const int* in_sizes, int n_in,
                              void* d_out, int out_size, void* d_ws, size_t ws_size,
                              hipStream_t stream) {
  const float* state = (const float*)d_in[0];
  const float* Wh    = (const float*)d_in[1];
  const float* bh    = (const float*)d_in[2];
  const float* Wout  = (const float*)d_in[3];
  const float* bout  = (const float*)d_in[4];
  float* out = (float*)d_out;

  build_tables<<<NL + 1, 64, 0, stream>>>(Wh, bh, Wout, bout, (char*)d_ws);

  // 131072 rows / 16 per wave = 8192 waves; 512-thr blocks -> 1024 blocks;
  // 4 blocks/CU -> 32 waves/CU = 8 waves/SIMD.
  policy_mfma<<<NB / 16 / 8, 512, 0, stream>>>(state, (const char*)d_ws, out);
}

// Round 12
// 46.589 us; speedup vs baseline: 1.4232x; 1.4232x over previous
//
#include <hip/hip_runtime.h>

// Policy MLP via split-precision bf16 MFMA (round 12: LDS + 8 waves/SIMD).
// B=131072, D=32, L=40 hidden + final 32->1.
//
// Round-12 = the experiment r10/r11 confounded: high occupancy AND LDS-fed
// weights. r11 showed weight fetch scales with wave count (4KB/layer/wave
// regardless of tile width): 32 waves/CU through L1 = ~52us of L1 service =
// the wall. Fix: feed from LDS (2x bandwidth, separate pipe) for as many
// layers as fit at 2 blocks/CU (79KB: bias-all + 18 layers), global L1 for
// the remaining 23 layers (~19us, overlappable).
//  * 16 batch cols/wave, 8192 waves, 1024-thr blocks x 512, 2 blocks/CU
//    -> 32 waves/CU = 8 waves/SIMD. __launch_bounds__(1024, 8).
//
// Math structure per layer (unchanged): 3-term split-precision
//   acc = Whi*xhi (C = fp32 bias) ; += Wlo*xhi ; += Whi*xlo
// k-permutation pi(g,j) = 4g+j (j<4) | 16+4g+(j-4), g=lane>>4, on both A
// and B so D's layout (col=lane&15, row=4g+reg) feeds next layer's B slots
// in-lane; truncation split via v_perm_b32 (hi's error carried by lo).

#define NB 131072
#define DD 32
#define NL 40
#define BIAS_BYTES ((NL + 1) * 32 * 4)       // 5248, compact fp32 bias
#define WTAB_OFF   BIAS_BYTES
#define WTAB_BYTES ((NL + 1) * 4 * 64 * 16)  // 167936
#define LDS_LAYERS 18
#define LDS_BYTES  (BIAS_BYTES + LDS_LAYERS * 4096)  // 78976 <= 81920 (2/CU)

typedef short bf16x8 __attribute__((ext_vector_type(8)));
typedef float f32x4 __attribute__((ext_vector_type(4)));

union Frag { int4 q; int i[4]; bf16x8 v; };
union BFrag { float4 q; f32x4 v; };

__device__ inline unsigned f2bf(float f) {  // fp32 -> bf16 bits, RNE
  unsigned u = __float_as_uint(f);
  return (u + 0x7fffu + ((u >> 16) & 1u)) >> 16;
}
__device__ inline float bf2f(unsigned s) { return __int_as_float((int)(s << 16)); }

// ---- table build ----------------------------------------------------------
// d_ws layout: [bias compact 5248 B][wtab 41 layers x 4096 B].
// wtab[l][p][lane]: p=0: W[m][pi] hi, p=1: W[16+m][pi] hi, p=2/3: lo parts.
__global__ __launch_bounds__(64) void build_tables(
    const float* __restrict__ Wh, const float* __restrict__ bh,
    const float* __restrict__ Wout, const float* __restrict__ bout,
    char* __restrict__ ws) {
  const int l = blockIdx.x;      // 0..40 (40 == output layer)
  const int lane = threadIdx.x;  // 0..63
  const int m = lane & 15, g = lane >> 4;
  int4* wtab = (int4*)(ws + WTAB_OFF);
  float* bc = (float*)ws;
  for (int p = 0; p < 4; ++p) {
    const int row = (p & 1) ? (16 + m) : m;
    const bool lopart = (p >= 2);
    int wds[4];
    for (int w = 0; w < 4; ++w) {
      unsigned wd = 0;
      for (int e = 0; e < 2; ++e) {
        const int j = 2 * w + e;
        const int k = (j < 4) ? (4 * g + j) : (16 + 4 * g + (j - 4));  // pi
        float v;
        if (l < NL) v = Wh[(l * 32 + row) * 32 + k];
        else        v = (row == 0) ? Wout[k] : 0.f;  // final: row0 = W_out
        unsigned hi = f2bf(v);
        unsigned val = lopart ? f2bf(v - bf2f(hi)) : hi;
        wd |= val << (16 * e);
      }
      wds[w] = (int)wd;
    }
    wtab[(l * 4 + p) * 64 + lane] = make_int4(wds[0], wds[1], wds[2], wds[3]);
  }
  if (lane < 32) {  // compact bias, one float per output row
    float bv = (l < NL) ? bh[l * 32 + lane] : ((lane == 0) ? bout[0] : 0.f);
    bc[l * 32 + lane] = bv;
  }
}

// ---- main kernel ----------------------------------------------------------
// Truncation split: hi = packed high-halves of (a,b) via one v_perm_b32;
// lo = packed high-halves of the exact residuals.
__device__ inline void split2(float a, float b, int& hi, int& lo) {
  const unsigned ia = __float_as_uint(a), ib = __float_as_uint(b);
  hi = (int)__builtin_amdgcn_perm(ia, ib, 0x03020706u);
  const float ha = __int_as_float((int)(ia & 0xffff0000u));
  const float hb = __int_as_float((int)(ib & 0xffff0000u));
  const float la = a - ha, lb = b - hb;  // exact
  lo = (int)__builtin_amdgcn_perm(__float_as_uint(la), __float_as_uint(lb),
                                  0x03020706u);
}

#define MFMA16(A, B, C) __builtin_amdgcn_mfma_f32_16x16x32_bf16((A), (B), (C), 0, 0, 0)

__global__ __launch_bounds__(1024, 8) void policy_mfma(
    const float* __restrict__ state, const char* __restrict__ tab,
    float* __restrict__ out) {
  extern __shared__ char smem[];
  const int tid = threadIdx.x;
  const int lane = tid & 63;
  const int n = lane & 15, g = lane >> 4;
  const int wid = blockIdx.x * 16 + (tid >> 6);
  const int bbase = wid * 16;  // 16 batch cols per wave

  // ---- stage bias + first 18 layers' weights into LDS (~79 KB) ----
  {
    const int4* src = (const int4*)tab;
    int4* dst = (int4*)smem;
    for (int i = tid; i < LDS_BYTES / 16; i += 1024) dst[i] = src[i];
  }

  // Layer-0 B frag from state (no LDS dependency; overlaps staging)
  Frag bhi, blo;
  {
    const float* xr = state + (size_t)(bbase + n) * DD;
    float4 xa = *(const float4*)(xr + 4 * g);
    float4 xc = *(const float4*)(xr + 16 + 4 * g);
    split2(xa.x, xa.y, bhi.i[0], blo.i[0]);
    split2(xa.z, xa.w, bhi.i[1], blo.i[1]);
    split2(xc.x, xc.y, bhi.i[2], blo.i[2]);
    split2(xc.z, xc.w, bhi.i[3], blo.i[3]);
  }

  __syncthreads();  // LDS tables ready

  const int4* lw = (const int4*)(smem + WTAB_OFF) + lane;  // LDS weights l<18
  const float* bc = (const float*)smem;                     // LDS bias, all l
  const int4* gw = (const int4*)(tab + WTAB_OFF) + lane;    // global l>=18

  auto layer = [&](int l, const int4* __restrict__ WP, int lofs) {
    Frag w0h, w1h, w0l, w1l;
    w0h.q = WP[lofs * 256 + 0];
    w1h.q = WP[lofs * 256 + 64];
    w0l.q = WP[lofs * 256 + 128];
    w1l.q = WP[lofs * 256 + 192];
    BFrag c0, c1;
    c0.q = *(const float4*)(bc + l * 32 + 4 * g);       // rows 4g..4g+3
    c1.q = *(const float4*)(bc + l * 32 + 16 + 4 * g);  // rows 16+4g..

    // two independent 3-deep chains
    f32x4 a0 = MFMA16(w0h.v, bhi.v, c0.v);
    f32x4 a1 = MFMA16(w1h.v, bhi.v, c1.v);
    a0 = MFMA16(w0l.v, bhi.v, a0);
    a1 = MFMA16(w1l.v, bhi.v, a1);
    a0 = MFMA16(w0h.v, blo.v, a0);
    a1 = MFMA16(w1h.v, blo.v, a1);

    // relu + trunc-split; a0 reg r -> slot r (rows 4g+r), a1 -> slot 4+r
    split2(fmaxf(a0[0], 0.f), fmaxf(a0[1], 0.f), bhi.i[0], blo.i[0]);
    split2(fmaxf(a0[2], 0.f), fmaxf(a0[3], 0.f), bhi.i[1], blo.i[1]);
    split2(fmaxf(a1[0], 0.f), fmaxf(a1[1], 0.f), bhi.i[2], blo.i[2]);
    split2(fmaxf(a1[2], 0.f), fmaxf(a1[3], 0.f), bhi.i[3], blo.i[3]);
  };

#pragma unroll
  for (int l = 0; l < LDS_LAYERS; ++l) layer(l, lw, l);       // LDS path
#pragma unroll
  for (int l = LDS_LAYERS; l < NL; ++l) layer(l, gw, l);      // global path

  // ---- final layer (W rows 16-31 zero: only w0h/w0l; row 0 = W_out) ----
  float res;
  {
    Frag w0h, w0l;
    w0h.q = gw[NL * 256 + 0];
    w0l.q = gw[NL * 256 + 128];
    BFrag c0;
    c0.q = *(const float4*)(bc + NL * 32 + 4 * g);
    f32x4 a0 = MFMA16(w0h.v, bhi.v, c0.v);
    a0 = MFMA16(w0l.v, bhi.v, a0);
    a0 = MFMA16(w0h.v, blo.v, a0);
    res = a0[0];  // row 0 lives in reg 0 of lanes g==0 (lane<16)
  }

  if (lane < 16) out[bbase + n] = res;
}

extern "C" void kernel_launch(void* const* d_in, const int* in_sizes, int n_in,
                              void* d_out, int out_size, void* d_ws, size_t ws_size,
                              hipStream_t stream) {
  const float* state = (const float*)d_in[0];
  const float* Wh    = (const float*)d_in[1];
  const float* bh    = (const float*)d_in[2];
  const float* Wout  = (const float*)d_in[3];
  const float* bout  = (const float*)d_in[4];
  float* out = (float*)d_out;

  build_tables<<<NL + 1, 64, 0, stream>>>(Wh, bh, Wout, bout, (char*)d_ws);

  // 8192 waves; 1024-thr blocks -> 512 blocks; 79KB LDS -> 2 blocks/CU
  // -> 32 waves/CU = 8 waves/SIMD.
  policy_mfma<<<512, 1024, LDS_BYTES, stream>>>(state, (const char*)d_ws, out);
}

// Round 13
// 44.016 us; speedup vs baseline: 1.5064x; 1.0585x over previous
//
#include <hip/hip_runtime.h>

// Policy MLP via split-precision bf16 MFMA (round 13: register prefetch).
// B=131072, D=32, L=40 hidden + final 32->1.
//
// Round-13 change vs round 10 (single variable): explicit double-buffered
// REGISTER prefetch of the next layer's weight + bias fragments.
// Evidence: r10/r12 VGPR_Count=36 -> compiler never hoisted the ds_reads;
// each wave-layer serially pays ~180 cyc LDS latency + 120 MFMA chain +
// ~70 split = ~380 cyc, and 4 waves/SIMD leave pipes at ~45%. Prefetch
// removes the LDS latency from the critical path. Parity-indexed buffers
// with full unroll => all indices static (no scratch, rule #20).
//
// Operating point (best measured): C=32 cols/wave, 16 waves/CU (1024-thr
// block, 1 block/CU via 157KB LDS), weights+bias for layers 0-37 in LDS,
// 38-40 via L1. __launch_bounds__(1024,4) -> 128-VGPR budget.
//
// Math per layer (unchanged): acc = Whi*xhi (C=bias); += Wlo*xhi; += Whi*xlo
// pi(g,j) = 4g+j (j<4) | 16+4g+(j-4) on both A and B => D feeds next B
// in-lane; truncation split via v_perm_b32.

#define NB 131072
#define DD 32
#define NL 40
#define BIAS_BYTES ((NL + 1) * 32 * 4)       // 5248, compact fp32 bias
#define WTAB_OFF   BIAS_BYTES
#define WTAB_BYTES ((NL + 1) * 4 * 64 * 16)  // 167936
#define LDS_LAYERS 38
#define LDS_BYTES  (BIAS_BYTES + LDS_LAYERS * 4096)  // 160896 <= 163840

typedef short bf16x8 __attribute__((ext_vector_type(8)));
typedef float f32x4 __attribute__((ext_vector_type(4)));

union Frag { int4 q; int i[4]; bf16x8 v; };
union BFrag { float4 q; f32x4 v; };

__device__ inline unsigned f2bf(float f) {  // fp32 -> bf16 bits, RNE
  unsigned u = __float_as_uint(f);
  return (u + 0x7fffu + ((u >> 16) & 1u)) >> 16;
}
__device__ inline float bf2f(unsigned s) { return __int_as_float((int)(s << 16)); }

// ---- table build ----------------------------------------------------------
// d_ws layout: [bias compact 5248 B][wtab 41 layers x 4096 B].
// wtab[l][p][lane]: p=0: W[m][pi] hi, p=1: W[16+m][pi] hi, p=2/3: lo parts.
__global__ __launch_bounds__(64) void build_tables(
    const float* __restrict__ Wh, const float* __restrict__ bh,
    const float* __restrict__ Wout, const float* __restrict__ bout,
    char* __restrict__ ws) {
  const int l = blockIdx.x;      // 0..40 (40 == output layer)
  const int lane = threadIdx.x;  // 0..63
  const int m = lane & 15, g = lane >> 4;
  int4* wtab = (int4*)(ws + WTAB_OFF);
  float* bc = (float*)ws;
  for (int p = 0; p < 4; ++p) {
    const int row = (p & 1) ? (16 + m) : m;
    const bool lopart = (p >= 2);
    int wds[4];
    for (int w = 0; w < 4; ++w) {
      unsigned wd = 0;
      for (int e = 0; e < 2; ++e) {
        const int j = 2 * w + e;
        const int k = (j < 4) ? (4 * g + j) : (16 + 4 * g + (j - 4));  // pi
        float v;
        if (l < NL) v = Wh[(l * 32 + row) * 32 + k];
        else        v = (row == 0) ? Wout[k] : 0.f;  // final: row0 = W_out
        unsigned hi = f2bf(v);
        unsigned val = lopart ? f2bf(v - bf2f(hi)) : hi;
        wd |= val << (16 * e);
      }
      wds[w] = (int)wd;
    }
    wtab[(l * 4 + p) * 64 + lane] = make_int4(wds[0], wds[1], wds[2], wds[3]);
  }
  if (lane < 32) {  // compact bias, one float per output row
    float bv = (l < NL) ? bh[l * 32 + lane] : ((lane == 0) ? bout[0] : 0.f);
    bc[l * 32 + lane] = bv;
  }
}

// ---- main kernel ----------------------------------------------------------
// Truncation split: hi = packed high-halves of (a,b) via one v_perm_b32;
// lo = packed high-halves of the exact residuals.
__device__ inline void split2(float a, float b, int& hi, int& lo) {
  const unsigned ia = __float_as_uint(a), ib = __float_as_uint(b);
  hi = (int)__builtin_amdgcn_perm(ia, ib, 0x03020706u);
  const float ha = __int_as_float((int)(ia & 0xffff0000u));
  const float hb = __int_as_float((int)(ib & 0xffff0000u));
  const float la = a - ha, lb = b - hb;  // exact
  lo = (int)__builtin_amdgcn_perm(__float_as_uint(la), __float_as_uint(lb),
                                  0x03020706u);
}

#define MFMA16(A, B, C) __builtin_amdgcn_mfma_f32_16x16x32_bf16((A), (B), (C), 0, 0, 0)

__global__ __launch_bounds__(1024, 4) void policy_mfma(
    const float* __restrict__ state, const char* __restrict__ tab,
    float* __restrict__ out) {
  extern __shared__ char smem[];
  const int tid = threadIdx.x;
  const int lane = tid & 63;
  const int n = lane & 15, g = lane >> 4;
  const int wid = blockIdx.x * 16 + (tid >> 6);
  const int bbase = wid * 32;  // 32 batch cols per wave (2 x 16-col tiles)

  // ---- stage bias + 38 layers of weights into LDS (~157 KB, one-time) ----
  {
    const int4* src = (const int4*)tab;
    int4* dst = (int4*)smem;
    for (int i = tid; i < LDS_BYTES / 16; i += 1024) dst[i] = src[i];
  }

  // Layer-0 B frags from state (no LDS dependency; overlaps staging)
  Frag bhi[2], blo[2];
#pragma unroll
  for (int t = 0; t < 2; ++t) {
    const float* xr = state + (size_t)(bbase + 16 * t + n) * DD;
    float4 xa = *(const float4*)(xr + 4 * g);
    float4 xc = *(const float4*)(xr + 16 + 4 * g);
    split2(xa.x, xa.y, bhi[t].i[0], blo[t].i[0]);
    split2(xa.z, xa.w, bhi[t].i[1], blo[t].i[1]);
    split2(xc.x, xc.y, bhi[t].i[2], blo[t].i[2]);
    split2(xc.z, xc.w, bhi[t].i[3], blo[t].i[3]);
  }

  __syncthreads();  // LDS tables ready

  const int4* lw = (const int4*)(smem + WTAB_OFF) + lane;  // LDS weights l<38
  const float* bc = (const float*)smem;                     // LDS bias, all l
  const int4* gw = (const int4*)(tab + WTAB_OFF) + lane;    // global l>=38

  // Double-buffered register prefetch (parity index; full unroll => static).
  Frag Wf[2][4];
  BFrag Cf[2][2];
  Wf[0][0].q = lw[0];
  Wf[0][1].q = lw[64];
  Wf[0][2].q = lw[128];
  Wf[0][3].q = lw[192];
  Cf[0][0].q = *(const float4*)(bc + 4 * g);
  Cf[0][1].q = *(const float4*)(bc + 16 + 4 * g);

#pragma unroll
  for (int l = 0; l < NL; ++l) {
    const int cur = l & 1, nxt = cur ^ 1;

    // ---- prefetch layer l+1 fragments into the other buffer ----
    {
      const int lp = l + 1;
      const int4* src = (lp < LDS_LAYERS) ? lw : gw;  // compile-time per iter
      Wf[nxt][0].q = src[lp * 256 + 0];
      Wf[nxt][1].q = src[lp * 256 + 64];
      Wf[nxt][2].q = src[lp * 256 + 128];
      Wf[nxt][3].q = src[lp * 256 + 192];
      Cf[nxt][0].q = *(const float4*)(bc + lp * 32 + 4 * g);
      Cf[nxt][1].q = *(const float4*)(bc + lp * 32 + 16 + 4 * g);
    }

    // ---- compute layer l: 4 independent 3-deep chains ----
    f32x4 a00 = MFMA16(Wf[cur][0].v, bhi[0].v, Cf[cur][0].v);
    f32x4 a01 = MFMA16(Wf[cur][1].v, bhi[0].v, Cf[cur][1].v);
    f32x4 a10 = MFMA16(Wf[cur][0].v, bhi[1].v, Cf[cur][0].v);
    f32x4 a11 = MFMA16(Wf[cur][1].v, bhi[1].v, Cf[cur][1].v);
    a00 = MFMA16(Wf[cur][2].v, bhi[0].v, a00);
    a01 = MFMA16(Wf[cur][3].v, bhi[0].v, a01);
    a10 = MFMA16(Wf[cur][2].v, bhi[1].v, a10);
    a11 = MFMA16(Wf[cur][3].v, bhi[1].v, a11);
    a00 = MFMA16(Wf[cur][0].v, blo[0].v, a00);
    a01 = MFMA16(Wf[cur][1].v, blo[0].v, a01);
    a10 = MFMA16(Wf[cur][0].v, blo[1].v, a10);
    a11 = MFMA16(Wf[cur][1].v, blo[1].v, a11);

    // relu + trunc-split; D reg r of accX0 -> slot j=r, accX1 -> slot 4+r
    split2(fmaxf(a00[0], 0.f), fmaxf(a00[1], 0.f), bhi[0].i[0], blo[0].i[0]);
    split2(fmaxf(a00[2], 0.f), fmaxf(a00[3], 0.f), bhi[0].i[1], blo[0].i[1]);
    split2(fmaxf(a01[0], 0.f), fmaxf(a01[1], 0.f), bhi[0].i[2], blo[0].i[2]);
    split2(fmaxf(a01[2], 0.f), fmaxf(a01[3], 0.f), bhi[0].i[3], blo[0].i[3]);
    split2(fmaxf(a10[0], 0.f), fmaxf(a10[1], 0.f), bhi[1].i[0], blo[1].i[0]);
    split2(fmaxf(a10[2], 0.f), fmaxf(a10[3], 0.f), bhi[1].i[1], blo[1].i[1]);
    split2(fmaxf(a11[0], 0.f), fmaxf(a11[1], 0.f), bhi[1].i[2], blo[1].i[2]);
    split2(fmaxf(a11[2], 0.f), fmaxf(a11[3], 0.f), bhi[1].i[3], blo[1].i[3]);
  }

  // ---- final layer l=40 (buffer parity NL&1 == 0). W rows 16-31 zero:
  // only frags 0 (hi, rows 0-15) and 2 (lo) + bias c0 needed; row0 = W_out.
  float res0, res1;
  {
    f32x4 a00 = MFMA16(Wf[0][0].v, bhi[0].v, Cf[0][0].v);
    f32x4 a10 = MFMA16(Wf[0][0].v, bhi[1].v, Cf[0][0].v);
    a00 = MFMA16(Wf[0][2].v, bhi[0].v, a00);
    a10 = MFMA16(Wf[0][2].v, bhi[1].v, a10);
    a00 = MFMA16(Wf[0][0].v, blo[0].v, a00);
    a10 = MFMA16(Wf[0][0].v, blo[1].v, a10);
    res0 = a00[0];  // row 0 lives in reg 0 of lanes g==0 (lane<16)
    res1 = a10[0];
  }

  if (lane < 16) {
    out[bbase + n] = res0;
    out[bbase + 16 + n] = res1;
  }
}

extern "C" void kernel_launch(void* const* d_in, const int* in_sizes, int n_in,
                              void* d_out, int out_size, void* d_ws, size_t ws_size,
                              hipStream_t stream) {
  const float* state = (const float*)d_in[0];
  const float* Wh    = (const float*)d_in[1];
  const float* bh    = (const float*)d_in[2];
  const float* Wout  = (const float*)d_in[3];
  const float* bout  = (const float*)d_in[4];
  float* out = (float*)d_out;

  build_tables<<<NL + 1, 64, 0, stream>>>(Wh, bh, Wout, bout, (char*)d_ws);

  // 4096 waves; 16 waves (1024 thr) per block; 256 blocks = 1/CU (LDS-pinned).
  policy_mfma<<<256, 1024, LDS_BYTES, stream>>>(state, (const char*)d_ws, out);
}